// Round 11
// baseline (513.077 us; speedup 1.0000x reference)
//
#include <hip/hip_runtime.h>
#include <hip/hip_fp16.h>
#include <math.h>

// ---------------------------------------------------------------------------
// NetGlobGATFix. R27: pad L0 to KP=64 -> all layers on the fused edge path.
//   - L0 was the last split attn+palpha layer (TPN=12 irregular at KP=48).
//     build_h0 constructs the input, so pad to 64 ch (34..63 zero); wesed/bt
//     built with Kp=64 (zero cols, same guard as k>=K); esed/gemm K=512.
//   - L0 now uses gat_fused_lds<8,64,4,16> (TPN=16, EC=2; 10000=625x16).
//     attn_kernel + gat_gather4 + palpha/zinv deleted.
//   - z-reduction for L0 becomes class-grouped shfl (same as L1-3, passing).
//   - Everything else identical to R26 (509.4us).
// ---------------------------------------------------------------------------

#define DEVFN static __device__ __forceinline__

typedef __attribute__((ext_vector_type(8))) _Float16 half8;
typedef __attribute__((ext_vector_type(4))) _Float16 half4v;
typedef __attribute__((ext_vector_type(4))) float f32x4;

DEVFN float selu_f(float v) {
    const float scale = 1.0507009873554805f;
    const float alpha = 1.6732632423543772f;
    return v > 0.f ? scale * v : scale * alpha * (expf(v) - 1.f);
}

DEVFN float lrelu02(float v) { return v > 0.f ? v : 0.2f * v; }

// ---------------- CNN (padded 66x66 layout) ----------------
#define PST 66
#define PSZ (66 * 66)

__global__ void pad_input(const float* __restrict__ cf, float* __restrict__ out) {
    int t = blockIdx.x * blockDim.x + threadIdx.x;
    if (t >= 4 * 4096) return;
    int c = t >> 12, pix = t & 4095;
    int y = pix >> 6, x = pix & 63;
    out[c * PSZ + (y + 1) * PST + (x + 1)] = cf[t];
}

template <int CIN>
__global__ __launch_bounds__(256) void conv3x3_pad(const float* __restrict__ in,
                                                   const float* __restrict__ w,
                                                   const float* __restrict__ b,
                                                   float* __restrict__ out) {
    int x  = threadIdx.x & 63;
    int yg = threadIdx.x >> 6;
    int y  = blockIdx.x * 4 + yg;          // 0..63
    int co = blockIdx.y;
    float acc = b[co];
    const float* wp = w + (size_t)co * CIN * 9;
#pragma unroll 4
    for (int ci = 0; ci < CIN; ++ci) {
        const float* ip = in + ci * PSZ + y * PST + x;
        const float* wr = wp + ci * 9;
        acc += wr[0] * ip[0]           + wr[1] * ip[1]           + wr[2] * ip[2]
             + wr[3] * ip[PST]         + wr[4] * ip[PST + 1]     + wr[5] * ip[PST + 2]
             + wr[6] * ip[2 * PST]     + wr[7] * ip[2 * PST + 1] + wr[8] * ip[2 * PST + 2];
    }
    out[(size_t)co * PSZ + (y + 1) * PST + (x + 1)] = selu_f(acc);
}

__global__ void avgpool_c(const float* __restrict__ in, float* __restrict__ gfeat) {
    int c = blockIdx.x;            // 24 blocks
    int t = threadIdx.x;           // 256 threads
    float s = 0.f;
    for (int i = t; i < 4096; i += 256) {
        int y = i >> 6, x = i & 63;
        s += in[c * PSZ + (y + 1) * PST + (x + 1)];
    }
#pragma unroll
    for (int off = 32; off >= 1; off >>= 1) s += __shfl_xor(s, off);
    __shared__ float red[4];
    int wave = t >> 6, lane = t & 63;
    if (lane == 0) red[wave] = s;
    __syncthreads();
    if (t == 0) gfeat[c] = (red[0] + red[1] + red[2] + red[3]) * (1.f / 4096.f);
}

// ---------------- node feature init (padded to 64 ch, fp16) + masks ---------
__global__ void build_h0(const float* __restrict__ x, const float* __restrict__ gfeat,
                         __half* __restrict__ h0f, unsigned* __restrict__ masks, int N) {
    int n = blockIdx.x * blockDim.x + threadIdx.x;
    if (n >= N) return;
    float x0 = x[n * 10 + 0], x1 = x[n * 10 + 1];
    unsigned mk = (x0 == 1.f ? 1u : 0u) | (x0 == 0.f ? 2u : 0u) |
                  (x1 == 0.f ? 4u : 0u) | (x1 == 1.f ? 8u : 0u);
    masks[n] = mk;
    __half* hq = h0f + (size_t)n * 64;
#pragma unroll
    for (int j = 0; j < 64; ++j) {
        float v = (j < 24) ? gfeat[j] : (j < 34 ? x[n * 10 + (j - 24)] : 0.f);
        hq[j] = __float2half(v);
    }
}

// ---------------- CSR build (parallel scan) ----------------
__global__ void count_dst(const int* __restrict__ ei, int* __restrict__ cnt, int E, int N) {
    int t = blockIdx.x * blockDim.x + threadIdx.x;
    if (t >= E + N) return;
    int dst = (t < E) ? ei[E + t] : (t - E);
    atomicAdd(&cnt[dst], 1);
}

__global__ void scan_blocks(const int* __restrict__ cnt, int* __restrict__ pref,
                            int* __restrict__ bsums, int n) {
    __shared__ int sdata[256];
    int i = blockIdx.x * 256 + threadIdx.x;
    int v = (i < n) ? cnt[i] : 0;
    sdata[threadIdx.x] = v;
    __syncthreads();
    for (int off = 1; off < 256; off <<= 1) {
        int tmp = (threadIdx.x >= off) ? sdata[threadIdx.x - off] : 0;
        __syncthreads();
        sdata[threadIdx.x] += tmp;
        __syncthreads();
    }
    if (i < n) pref[i] = sdata[threadIdx.x] - v;
    if (threadIdx.x == 255) bsums[blockIdx.x] = sdata[255];
}

__global__ void scan_sums(int* __restrict__ bsums, int nb) {
    int tid = threadIdx.x;                 // 64
    int orig = (tid < nb) ? bsums[tid] : 0;
    int v = orig;
#pragma unroll
    for (int off = 1; off < 64; off <<= 1) {
        int u = __shfl_up(v, off);
        if (tid >= off) v += u;
    }
    if (tid < nb) bsums[tid] = v - orig;
}

__global__ void scan_apply(const int* __restrict__ pref, const int* __restrict__ bsums,
                           int* __restrict__ indptr, int* __restrict__ cursor,
                           int n, int total) {
    int i = blockIdx.x * 256 + threadIdx.x;
    if (i == 0) indptr[n] = total;
    if (i >= n) return;
    int e = bsums[blockIdx.x] + pref[i];
    indptr[i] = e;
    cursor[i] = e;
}

__global__ void scatter_edges(const int* __restrict__ ei, int* __restrict__ cursor,
                              int* __restrict__ col, int E, int N) {
    int t = blockIdx.x * blockDim.x + threadIdx.x;
    if (t >= E + N) return;
    int src, dst;
    if (t < E) { src = ei[t]; dst = ei[E + t]; }
    else       { src = dst = t - E; }
    int pos = atomicAdd(&cursor[dst], 1);
    col[pos] = src;
}

// ---------------- fused one-shot weight prep --------------------------------
// bt layout per layer: bt[btOff + m*KA + h*Kp + k] = fp16(W[k*HC + h*C + m])
// wesed[weOff + k*2H + o] = sum_c W[k,h*C+c]*a[h,c]  (h=o%H, a=as/ad by o<H).
// wcomb (layer 4, 128x64): cols 0..31 = es/ed weights, cols 32..63 = W4 cols.
__global__ __launch_bounds__(256) void prep_all(
        const float* __restrict__ W0, const float* __restrict__ W1,
        const float* __restrict__ W2, const float* __restrict__ W3,
        const float* __restrict__ W4,
        const float* __restrict__ as0, const float* __restrict__ as1,
        const float* __restrict__ as2, const float* __restrict__ as3,
        const float* __restrict__ as4,
        const float* __restrict__ ad0, const float* __restrict__ ad1,
        const float* __restrict__ ad2, const float* __restrict__ ad3,
        const float* __restrict__ ad4,
        unsigned short* __restrict__ bt, float* __restrict__ wesed,
        float* __restrict__ wcomb) {
    const int Kc[5]  = {34, 64, 128, 256, 128};
    const int Kpc[5] = {64, 64, 128, 256, 128};        // L0 padded to 64
    const int Hc[5]  = {8, 16, 8, 8, 16};
    const int Cc[5]  = {64, 128, 256, 128, 2};
    const int HCc[5] = {512, 2048, 2048, 1024, 32};
    const int KAc[5] = {512, 1024, 1024, 2048, 2048};  // L0 KA = 8*64
    const int btOff[5] = {0, 32768, 163840, 425984, 0};
    const int weOff[5] = {0, 1024, 3072, 5120, 9216};

    int b = blockIdx.x, tid = threadIdx.x;

    if (b < 168) {
        // ---- LDS-tiled transpose, one (layer, head, 64x64 tile) per block --
        int lyr, tloc;
        if (b < 8)        { lyr = 0; tloc = b; }
        else if (b < 40)  { lyr = 1; tloc = b - 8; }
        else if (b < 104) { lyr = 2; tloc = b - 40; }
        else              { lyr = 3; tloc = b - 104; }
        const int ktl[4] = {1, 1, 2, 4};   // ceil(Kp/64)
        const int mtl[4] = {1, 2, 4, 2};   // ceil(C/64)
        int kt = ktl[lyr], mt = mtl[lyr];
        int per_h = kt * mt;
        int h = tloc / per_h, r = tloc - h * per_h;
        int ki = r % kt, mi = r / kt;
        int k0 = ki * 64, m0 = mi * 64;
        int K = Kc[lyr], Kp = Kpc[lyr], C = Cc[lyr], HC = HCc[lyr], KA = KAc[lyr];
        const float* W;
        if (lyr == 0) W = W0; else if (lyr == 1) W = W1;
        else if (lyr == 2) W = W2; else W = W3;

        __shared__ float tile[64][65];
        int c = tid & 63, rg = tid >> 6;
        for (int r2 = rg; r2 < 64; r2 += 4) {       // coalesced 256B reads
            int k = k0 + r2, m = m0 + c;
            float v = (k < K && m < C) ? W[(size_t)k * HC + h * C + m] : 0.f;
            tile[r2][c] = v;
        }
        __syncthreads();
        unsigned short* bp = bt + btOff[lyr];
        for (int mr = rg; mr < 64; mr += 4) {       // coalesced 128B fp16 writes
            int m = m0 + mr, k = k0 + c;
            if (m < C && k < Kp)
                bp[(size_t)m * KA + h * Kp + k] =
                    __half_as_ushort(__float2half(tile[c][mr]));
        }
    } else if (b < 200) {
        // ---- wcomb for layer 4: 8192 outputs (128 x 64) ----
        int u = (b - 168) * 256 + tid;
        int k = u >> 6, o = u & 63;
        float s;
        if (o < 32) {                       // es/ed weights
            int h = (o < 16) ? o : o - 16;
            const float* av = ((o < 16) ? as4 : ad4) + h * 2;
            s = W4[k * 32 + h * 2 + 0] * av[0] + W4[k * 32 + h * 2 + 1] * av[1];
        } else {                            // y projection: raw W4 column
            s = W4[k * 32 + (o - 32)];
        }
        wcomb[u] = s;
    } else {
        // ---- wesed dots: sizes {1024,2048,2048,4096,4096} -> 52 blocks ----
        int wb = b - 200;
        int lyr, u0;
        if (wb < 4)       { lyr = 0; u0 = wb * 256; }
        else if (wb < 12) { lyr = 1; u0 = (wb - 4) * 256; }
        else if (wb < 20) { lyr = 2; u0 = (wb - 12) * 256; }
        else if (wb < 36) { lyr = 3; u0 = (wb - 20) * 256; }
        else              { lyr = 4; u0 = (wb - 36) * 256; }
        int u = u0 + tid;
        int K = Kc[lyr], Kp = Kpc[lyr], H = Hc[lyr], C = Cc[lyr], HC = HCc[lyr];
        int H2 = 2 * H;
        if (u < Kp * H2) {
            int k = u / H2, o = u - k * H2;
            float s = 0.f;
            if (k < K) {
                int h = (o < H) ? o : o - H;
                const float *W, *as_, *ad_;
                if (lyr == 0)      { W = W0; as_ = as0; ad_ = ad0; }
                else if (lyr == 1) { W = W1; as_ = as1; ad_ = ad1; }
                else if (lyr == 2) { W = W2; as_ = as2; ad_ = ad2; }
                else if (lyr == 3) { W = W3; as_ = as3; ad_ = ad3; }
                else               { W = W4; as_ = as4; ad_ = ad4; }
                const float* av = ((o < H) ? as_ : ad_) + h * C;
                const float* wp = W + (size_t)k * HC + h * C;
#pragma unroll 4
                for (int c2 = 0; c2 < C; ++c2) s += wp[c2] * av[c2];
            }
            wesed[weOff[lyr] + u] = s;
        }
    }
}

// ---------------- es/ed (and eyp): out[n,o] = hin16[n,:] @ w[:,o] -----------
__global__ void esed_kernel(const __half* __restrict__ hin, const float* __restrict__ wesed,
                            float* __restrict__ esed, int N, int Kp, int H2) {
    int t = blockIdx.x * blockDim.x + threadIdx.x;
    if (t >= N * H2) return;
    int n = t / H2, o = t - n * H2;
    const __half2* hp = (const __half2*)(hin + (size_t)n * Kp);
    float s = 0.f;
    for (int k2 = 0; k2 < Kp / 2; ++k2) {
        float2 f = __half22float2(hp[k2]);
        s += f.x * wesed[(2 * k2) * H2 + o] + f.y * wesed[(2 * k2 + 1) * H2 + o];
    }
    esed[t] = s;
}

// -------- fused attn+gather via LDS broadcast (layers 0-3) ------------------
// TPN = KP/CH lanes per node (16/32/64; node groups never cross waves).
// Per chunk of EC = TPN/H edges:
//   phase A: lane j -> (e=j/H, h=j%H): p = exp(lrelu(es[src,h]+ed[n,h])),
//            zloc += p, store p -> lds_p[sub][j].
//   phase B: pipelined gather; alphas broadcast via float4 ds_reads.
// z reduced over lane classes by shfl_xor strides H..TPN/2.
template <int H, int KP, int CH, int NPB>
__global__ __launch_bounds__(NPB * (KP / CH)) void gat_fused_lds(
        const __half* __restrict__ hinf, const float* __restrict__ esed,
        const int* __restrict__ indptr, const int* __restrict__ col,
        __half* __restrict__ g, int N) {
    const int TPN = KP / CH;
    const int EC  = TPN / H;
    const int H2  = 2 * H;
    __shared__ float lds_p[NPB][TPN];
    int sub = threadIdx.x / TPN;
    int j   = threadIdx.x % TPN;
    int n = blockIdx.x * NPB + sub;
    if (n >= N) return;
    int e_my = j / H, h_my = j % H;
    int c0 = j * CH;
    float edv = esed[n * H2 + H + h_my];

    float acc[H][CH];
#pragma unroll
    for (int h = 0; h < H; ++h)
#pragma unroll
        for (int t = 0; t < CH; ++t) acc[h][t] = 0.f;
    float zloc = 0.f;

    int beg = indptr[n], deg = indptr[n + 1] - beg;
    for (int base = 0; base < deg; base += EC) {
        // ---- phase A: p values for this chunk -> LDS ----
        int ce = base + e_my;
        float p = 0.f;
        if (ce < deg) {
            int srcm = col[beg + ce];
            p = expf(lrelu02(esed[srcm * H2 + h_my] + edv));
        }
        zloc += p;
        lds_p[sub][j] = p;
        __builtin_amdgcn_wave_barrier();
        // ---- phase B: pipelined gather with LDS-broadcast alphas ----
#pragma unroll
        for (int e = 0; e < EC; ++e) {
            int idx = base + e;
            if (idx < deg) {                  // uniform within node group
                int src = col[beg + idx];
                float f[CH];
                if (CH == 2) {
                    __half2 hv = *(const __half2*)(hinf + (size_t)src * KP + c0);
                    float2 ff = __half22float2(hv);
                    f[0] = ff.x; f[1] = ff.y;
                } else {
                    half4v hv = *(const half4v*)(hinf + (size_t)src * KP + c0);
                    f[0] = (float)hv[0]; f[1] = (float)hv[1];
                    f[2] = (float)hv[2]; f[3] = (float)hv[3];
                }
                const float4* ap = (const float4*)&lds_p[sub][e * H];
#pragma unroll
                for (int q4 = 0; q4 < H / 4; ++q4) {
                    float4 a4 = ap[q4];
#pragma unroll
                    for (int t = 0; t < CH; ++t) {
                        acc[4 * q4 + 0][t] += a4.x * f[t];
                        acc[4 * q4 + 1][t] += a4.y * f[t];
                        acc[4 * q4 + 2][t] += a4.z * f[t];
                        acc[4 * q4 + 3][t] += a4.w * f[t];
                    }
                }
            }
        }
        __builtin_amdgcn_wave_barrier();
    }

    // z: reduce across the EC lanes of each head class
#pragma unroll
    for (int off = H; off < TPN; off <<= 1)
        zloc += __shfl_xor(zloc, off, TPN);
    float zinv_my = (1.f / H) / (zloc + 1e-16f);

    __half* gp = g + (size_t)n * (H * KP) + c0;
#pragma unroll
    for (int h = 0; h < H; ++h) {
        float zf = __shfl(zinv_my, h, TPN);   // lane class h holds z for head h
        if (CH == 2) {
            *(__half2*)(gp + h * KP) =
                __floats2half2_rn(acc[h][0] * zf, acc[h][1] * zf);
        } else {
            __half2 lo = __floats2half2_rn(acc[h][0] * zf, acc[h][1] * zf);
            __half2 hi = __floats2half2_rn(acc[h][2] * zf, acc[h][3] * zf);
            union { __half2 h2[2]; float2 f2; } u;
            u.h2[0] = lo; u.h2[1] = hi;
            *(float2*)(gp + h * KP) = u.f2;
        }
    }
}

// -------- layer 4: fused attention + projected gather + output --------------
template <int NPB>
__global__ __launch_bounds__(NPB * 32) void final_attn(
        const float* __restrict__ eyp, const int* __restrict__ indptr,
        const int* __restrict__ col, const float* __restrict__ b5,
        const unsigned* __restrict__ masks, const float* __restrict__ x,
        float* __restrict__ outp, int N) {
    int sub = threadIdx.x >> 5;
    int j   = threadIdx.x & 31;
    int n = blockIdx.x * NPB + sub;
    if (n >= N) return;
    int h = j >> 1;
    float edv = eyp[(size_t)n * 64 + 16 + h];
    int beg = indptr[n], end = indptr[n + 1];
    float z = 0.f, a = 0.f;
    int i = beg;
    for (; i + 1 < end; i += 2) {
        int s0 = col[i], s1 = col[i + 1];
        const float* r0 = eyp + (size_t)s0 * 64;
        const float* r1 = eyp + (size_t)s1 * 64;
        float es0 = r0[h], y0 = r0[32 + j];
        float es1 = r1[h], y1 = r1[32 + j];
        float p0 = expf(lrelu02(es0 + edv));
        float p1 = expf(lrelu02(es1 + edv));
        z += p0; a += p0 * y0;
        z += p1; a += p1 * y1;
    }
    for (; i < end; ++i) {
        const float* r = eyp + (size_t)col[i] * 64;
        float p = expf(lrelu02(r[h] + edv));
        z += p; a += p * r[32 + j];
    }
    float zf = (1.f / 16.f) / (z + 1e-16f);
    float val = a * zf;
#pragma unroll
    for (int off = 2; off <= 16; off <<= 1) val += __shfl_xor(val, off, 32);
    float other = __shfl_xor(val, 1, 32);        // opposite parity's sum
    if (j == 0) {
        unsigned mk = masks[n];
        float v0 = x[n * 10 + 0] + selu_f(val + b5[0]);
        float v1 = x[n * 10 + 1] + selu_f(other + b5[1]);
        if (mk & 2u) v0 = 0.f; else if (mk & 1u) v0 = 1.f;
        if (mk & 8u) v1 = 1.f; else if (mk & 4u) v1 = 0.f;
        outp[n * 2 + 0] = v0;
        outp[n * 2 + 1] = v1;
    }
}

// ---------------- LDS-staged f16 MFMA GEMM (64x64 tile, BK=64) --------------
#define LDP 72
__global__ __launch_bounds__(256) void gemm_lds(const __half* __restrict__ A,
                                                const unsigned short* __restrict__ Bhi,
                                                const float* __restrict__ bias,
                                                const unsigned* __restrict__ masks,
                                                __half* __restrict__ O16,
                                                int N, int K, int M) {
    __shared__ __half lA[64 * LDP], lB[64 * LDP];
    int tid = threadIdx.x;
    int wave = tid >> 6, lane = tid & 63;
    int ln16 = lane & 15, q = lane >> 4;
    int row0 = blockIdx.x * 64;
    int col0 = blockIdx.y * 64;

    int r0 = tid >> 3, r1 = r0 + 32;
    int ac = (tid & 7) * 8;                      // col offset in halves
    int ga0 = min(row0 + r0, N - 1);
    int ga1 = min(row0 + r1, N - 1);
    const __half* Bp = (const __half*)Bhi;
    const __half* a0p = A + (size_t)ga0 * K + ac;
    const __half* a1p = A + (size_t)ga1 * K + ac;
    const __half* b0p = Bp + (size_t)(col0 + r0) * K + ac;
    const __half* b1p = Bp + (size_t)(col0 + r1) * K + ac;

    half8 ra0 = *(const half8*)(a0p);
    half8 ra1 = *(const half8*)(a1p);
    half8 rb0 = *(const half8*)(b0p);
    half8 rb1 = *(const half8*)(b1p);

    f32x4 acc[4];
#pragma unroll
    for (int j = 0; j < 4; ++j) acc[j] = (f32x4){0.f, 0.f, 0.f, 0.f};

    for (int kc = 0; kc < K; kc += 64) {
        __syncthreads();
        *(half8*)(lA + r0 * LDP + ac) = ra0;
        *(half8*)(lA + r1 * LDP + ac) = ra1;
        *(half8*)(lB + r0 * LDP + ac) = rb0;
        *(half8*)(lB + r1 * LDP + ac) = rb1;
        __syncthreads();
        int kn = kc + 64;
        if (kn < K) {
            ra0 = *(const half8*)(a0p + kn);
            ra1 = *(const half8*)(a1p + kn);
            rb0 = *(const half8*)(b0p + kn);
            rb1 = *(const half8*)(b1p + kn);
        }
#pragma unroll
        for (int kk = 0; kk < 2; ++kk) {
            half8 af = *(const half8*)(lA + (wave * 16 + ln16) * LDP + kk * 32 + q * 8);
#pragma unroll
            for (int j = 0; j < 4; ++j) {
                half8 bf = *(const half8*)(lB + (j * 16 + ln16) * LDP + kk * 32 + q * 8);
                acc[j] = __builtin_amdgcn_mfma_f32_16x16x32_f16(af, bf, acc[j], 0, 0, 0);
            }
        }
    }

#pragma unroll
    for (int j = 0; j < 4; ++j) {
        int cc = col0 + j * 16 + ln16;
        float bv = bias[cc];
#pragma unroll
        for (int r = 0; r < 4; ++r) {
            int rr = row0 + wave * 16 + q * 4 + r;
            if (rr >= N) continue;
            float v = selu_f(acc[j][r] + bv);
            if (cc < 2) {
                unsigned mk = masks[rr];
                if (cc == 0) { if (mk & 2u) v = 0.f; else if (mk & 1u) v = 1.f; }
                else         { if (mk & 8u) v = 1.f; else if (mk & 4u) v = 0.f; }
            }
            O16[(size_t)rr * M + cc] = __float2half(v);
        }
    }
}

// ---------------------------------------------------------------------------
extern "C" void kernel_launch(void* const* d_in, const int* in_sizes, int n_in,
                              void* d_out, int out_size, void* d_ws, size_t ws_size,
                              hipStream_t stream) {
    const float* x   = (const float*)d_in[0];
    const int*   ei  = (const int*)d_in[1];
    const float* cf  = (const float*)d_in[2];
    const float* cw[4] = {(const float*)d_in[3], (const float*)d_in[5],
                          (const float*)d_in[7], (const float*)d_in[9]};
    const float* cb[4] = {(const float*)d_in[4], (const float*)d_in[6],
                          (const float*)d_in[8], (const float*)d_in[10]};
    const float* gw[5], *gas[5], *gad[5], *gb[5];
    for (int i = 0; i < 5; ++i) {
        gw[i]  = (const float*)d_in[11 + 4 * i];
        gas[i] = (const float*)d_in[12 + 4 * i];
        gad[i] = (const float*)d_in[13 + 4 * i];
        gb[i]  = (const float*)d_in[14 + 4 * i];
    }
    const int N = in_sizes[0] / 10;        // 10000
    const int E = in_sizes[1] / 2;         // 160000
    const int EN = E + N;
    const int NB = (N + 255) / 256;        // scan blocks (40)

    // ---- workspace carve-up ----
    char* base = (char*)d_ws;
    size_t off = 0;
    auto alloc = [&](size_t bytes) -> char* {
        char* p = base + off;
        off = (off + bytes + 255) & ~(size_t)255;
        return p;
    };
    float* cfp   = (float*)alloc((size_t)4 * PSZ * 4);
    float* c1p   = (float*)alloc((size_t)16 * PSZ * 4);
    float* c2p   = (float*)alloc((size_t)32 * PSZ * 4);
    float* c3p   = (float*)alloc((size_t)64 * PSZ * 4);
    float* c4p   = (float*)alloc((size_t)24 * PSZ * 4);
    float* gfeat = (float*)alloc(24 * 4);
    __half* hA16 = (__half*)alloc((size_t)N * 256 * 2);
    __half* hB16 = (__half*)alloc((size_t)N * 256 * 2);
    __half* g    = (__half*)alloc((size_t)N * 2048 * 2);
    float* esed  = (float*)alloc((size_t)N * 32 * 4);
    float* eyp   = (float*)alloc((size_t)N * 64 * 4);        // L4 [es|ed|y]
    float* wesed = (float*)alloc((size_t)13312 * 4);         // layers 0-4
    float* wcomb = (float*)alloc((size_t)8192 * 4);          // L4 combined weights
    unsigned short* bt = (unsigned short*)alloc((size_t)688128 * 2);  // 4 GEMM layers
    unsigned* masks = (unsigned*)alloc((size_t)N * 4);
    int* cnt    = (int*)alloc((size_t)N * 4);
    int* pref   = (int*)alloc((size_t)N * 4);
    int* bsums  = (int*)alloc(64 * 4);
    int* indptr = (int*)alloc((size_t)(N + 1) * 4);
    int* cursor = (int*)alloc((size_t)N * 4);
    int* col    = (int*)alloc((size_t)EN * 4);
    (void)ws_size; // ~70 MB

    // ---- one-shot fused weight prep (all 5 layers) ----
    prep_all<<<252, 256, 0, stream>>>(gw[0], gw[1], gw[2], gw[3], gw[4],
                                      gas[0], gas[1], gas[2], gas[3], gas[4],
                                      gad[0], gad[1], gad[2], gad[3], gad[4],
                                      bt, wesed, wcomb);

    // ---- CNN (padded layout; single memset zeroes all borders) ----
    hipMemsetAsync(cfp, 0, (size_t)140 * PSZ * 4, stream);
    pad_input<<<(4 * 4096 + 255) / 256, 256, 0, stream>>>(cf, cfp);
    conv3x3_pad<4><<<dim3(16, 16), 256, 0, stream>>>(cfp, cw[0], cb[0], c1p);
    conv3x3_pad<16><<<dim3(16, 32), 256, 0, stream>>>(c1p, cw[1], cb[1], c2p);
    conv3x3_pad<32><<<dim3(16, 64), 256, 0, stream>>>(c2p, cw[2], cb[2], c3p);
    conv3x3_pad<64><<<dim3(16, 24), 256, 0, stream>>>(c3p, cw[3], cb[3], c4p);
    avgpool_c<<<24, 256, 0, stream>>>(c4p, gfeat);

    // ---- h0 (padded to 64, fp16) + masks ----
    build_h0<<<(N + 255) / 256, 256, 0, stream>>>(x, gfeat, hA16, masks, N);

    // ---- CSR by dst (incl self loops), parallel scan ----
    hipMemsetAsync(cnt, 0, (size_t)N * 4, stream);
    count_dst<<<(EN + 255) / 256, 256, 0, stream>>>(ei, cnt, E, N);
    scan_blocks<<<NB, 256, 0, stream>>>(cnt, pref, bsums, N);
    scan_sums<<<1, 64, 0, stream>>>(bsums, NB);
    scan_apply<<<NB, 256, 0, stream>>>(pref, bsums, indptr, cursor, N, EN);
    scatter_edges<<<(EN + 255) / 256, 256, 0, stream>>>(ei, cursor, col, E, N);

    // ---- GAT layers ----
    const int Hs[5] = {8, 16, 8, 8, 16};
    const int Cs[5] = {64, 128, 256, 128, 2};
    const int Kp[5] = {64, 64, 128, 256, 128};
    const int btOffA[5] = {0, 32768, 163840, 425984, 0};
    const int weOffA[5] = {0, 1024, 3072, 5120, 9216};

    const __half* hin16 = hA16;
    __half* hout16[4]  = {hB16, hA16, hB16, hA16};

    for (int lyr = 0; lyr < 5; ++lyr) {
        int KP = Kp[lyr], H = Hs[lyr], C = Cs[lyr];
        int KA = H * KP;
        if (lyr == 4) {
            // project-first fused final layer
            esed_kernel<<<(N * 64 + 255) / 256, 256, 0, stream>>>(hin16, wcomb, eyp,
                                                                  N, 128, 64);
            final_attn<8><<<(N + 7) / 8, 256, 0, stream>>>(eyp, indptr, col, gb[4],
                                                           masks, x, (float*)d_out, N);
            break;
        }
        esed_kernel<<<(N * 2 * H + 255) / 256, 256, 0, stream>>>(hin16, wesed + weOffA[lyr],
                                                                 esed, N, KP, 2 * H);
        if (lyr == 0) {
            gat_fused_lds<8, 64, 4, 16><<<(N + 15) / 16, 256, 0, stream>>>(
                hin16, esed, indptr, col, g, N);
        } else if (lyr == 1) {
            gat_fused_lds<16, 64, 2, 8><<<(N + 7) / 8, 256, 0, stream>>>(
                hin16, esed, indptr, col, g, N);
        } else if (lyr == 2) {
            gat_fused_lds<8, 128, 4, 8><<<(N + 7) / 8, 256, 0, stream>>>(
                hin16, esed, indptr, col, g, N);
        } else {
            gat_fused_lds<8, 256, 4, 4><<<(N + 3) / 4, 256, 0, stream>>>(
                hin16, esed, indptr, col, g, N);
        }

        const unsigned short* btL = bt + btOffA[lyr];
        int gx = (N + 63) / 64;        // 157
        gemm_lds<<<dim3(gx, C / 64), 256, 0, stream>>>(g, btL, gb[lyr], masks,
                                                       hout16[lyr], N, KA, C);
        hin16 = hout16[lyr];
    }
}

// Round 12
// 506.829 us; speedup vs baseline: 1.0123x; 1.0123x over previous
//
#include <hip/hip_runtime.h>
#include <hip/hip_fp16.h>
#include <math.h>

// ---------------------------------------------------------------------------
// NetGlobGATFix. R28: gemm col-widening + gather phase-A pipelining.
//   - gemm_rc: 32x128 tile (4 waves = 2 row-halves x 2 col-halves, per-wave
//     shape identical to old 16x64) -> A-reads for L1-3 halve (~50MB saved),
//     grid 313 blocks (no occupancy loss). Bit-identical MFMA sequence.
//   - gat_fused_lds: double-buffered lds_p; next chunk's col+esed loads
//     issued before phase B, exp computed after -> attention-load latency
//     hides under gather FMAs. zloc/acc order unchanged.
//   - Everything else identical to R27 (513.1us; best 509.4).
// ---------------------------------------------------------------------------

#define DEVFN static __device__ __forceinline__

typedef __attribute__((ext_vector_type(8))) _Float16 half8;
typedef __attribute__((ext_vector_type(4))) _Float16 half4v;
typedef __attribute__((ext_vector_type(4))) float f32x4;

DEVFN float selu_f(float v) {
    const float scale = 1.0507009873554805f;
    const float alpha = 1.6732632423543772f;
    return v > 0.f ? scale * v : scale * alpha * (expf(v) - 1.f);
}

DEVFN float lrelu02(float v) { return v > 0.f ? v : 0.2f * v; }

// ---------------- CNN (padded 66x66 layout) ----------------
#define PST 66
#define PSZ (66 * 66)

__global__ void pad_input(const float* __restrict__ cf, float* __restrict__ out) {
    int t = blockIdx.x * blockDim.x + threadIdx.x;
    if (t >= 4 * 4096) return;
    int c = t >> 12, pix = t & 4095;
    int y = pix >> 6, x = pix & 63;
    out[c * PSZ + (y + 1) * PST + (x + 1)] = cf[t];
}

template <int CIN>
__global__ __launch_bounds__(256) void conv3x3_pad(const float* __restrict__ in,
                                                   const float* __restrict__ w,
                                                   const float* __restrict__ b,
                                                   float* __restrict__ out) {
    int x  = threadIdx.x & 63;
    int yg = threadIdx.x >> 6;
    int y  = blockIdx.x * 4 + yg;          // 0..63
    int co = blockIdx.y;
    float acc = b[co];
    const float* wp = w + (size_t)co * CIN * 9;
#pragma unroll 4
    for (int ci = 0; ci < CIN; ++ci) {
        const float* ip = in + ci * PSZ + y * PST + x;
        const float* wr = wp + ci * 9;
        acc += wr[0] * ip[0]           + wr[1] * ip[1]           + wr[2] * ip[2]
             + wr[3] * ip[PST]         + wr[4] * ip[PST + 1]     + wr[5] * ip[PST + 2]
             + wr[6] * ip[2 * PST]     + wr[7] * ip[2 * PST + 1] + wr[8] * ip[2 * PST + 2];
    }
    out[(size_t)co * PSZ + (y + 1) * PST + (x + 1)] = selu_f(acc);
}

__global__ void avgpool_c(const float* __restrict__ in, float* __restrict__ gfeat) {
    int c = blockIdx.x;            // 24 blocks
    int t = threadIdx.x;           // 256 threads
    float s = 0.f;
    for (int i = t; i < 4096; i += 256) {
        int y = i >> 6, x = i & 63;
        s += in[c * PSZ + (y + 1) * PST + (x + 1)];
    }
#pragma unroll
    for (int off = 32; off >= 1; off >>= 1) s += __shfl_xor(s, off);
    __shared__ float red[4];
    int wave = t >> 6, lane = t & 63;
    if (lane == 0) red[wave] = s;
    __syncthreads();
    if (t == 0) gfeat[c] = (red[0] + red[1] + red[2] + red[3]) * (1.f / 4096.f);
}

// ---------------- node feature init (padded to 64 ch, fp16) + masks ---------
__global__ void build_h0(const float* __restrict__ x, const float* __restrict__ gfeat,
                         __half* __restrict__ h0f, unsigned* __restrict__ masks, int N) {
    int n = blockIdx.x * blockDim.x + threadIdx.x;
    if (n >= N) return;
    float x0 = x[n * 10 + 0], x1 = x[n * 10 + 1];
    unsigned mk = (x0 == 1.f ? 1u : 0u) | (x0 == 0.f ? 2u : 0u) |
                  (x1 == 0.f ? 4u : 0u) | (x1 == 1.f ? 8u : 0u);
    masks[n] = mk;
    __half* hq = h0f + (size_t)n * 64;
#pragma unroll
    for (int j = 0; j < 64; ++j) {
        float v = (j < 24) ? gfeat[j] : (j < 34 ? x[n * 10 + (j - 24)] : 0.f);
        hq[j] = __float2half(v);
    }
}

// ---------------- CSR build (parallel scan) ----------------
__global__ void count_dst(const int* __restrict__ ei, int* __restrict__ cnt, int E, int N) {
    int t = blockIdx.x * blockDim.x + threadIdx.x;
    if (t >= E + N) return;
    int dst = (t < E) ? ei[E + t] : (t - E);
    atomicAdd(&cnt[dst], 1);
}

__global__ void scan_blocks(const int* __restrict__ cnt, int* __restrict__ pref,
                            int* __restrict__ bsums, int n) {
    __shared__ int sdata[256];
    int i = blockIdx.x * 256 + threadIdx.x;
    int v = (i < n) ? cnt[i] : 0;
    sdata[threadIdx.x] = v;
    __syncthreads();
    for (int off = 1; off < 256; off <<= 1) {
        int tmp = (threadIdx.x >= off) ? sdata[threadIdx.x - off] : 0;
        __syncthreads();
        sdata[threadIdx.x] += tmp;
        __syncthreads();
    }
    if (i < n) pref[i] = sdata[threadIdx.x] - v;
    if (threadIdx.x == 255) bsums[blockIdx.x] = sdata[255];
}

__global__ void scan_sums(int* __restrict__ bsums, int nb) {
    int tid = threadIdx.x;                 // 64
    int orig = (tid < nb) ? bsums[tid] : 0;
    int v = orig;
#pragma unroll
    for (int off = 1; off < 64; off <<= 1) {
        int u = __shfl_up(v, off);
        if (tid >= off) v += u;
    }
    if (tid < nb) bsums[tid] = v - orig;
}

__global__ void scan_apply(const int* __restrict__ pref, const int* __restrict__ bsums,
                           int* __restrict__ indptr, int* __restrict__ cursor,
                           int n, int total) {
    int i = blockIdx.x * 256 + threadIdx.x;
    if (i == 0) indptr[n] = total;
    if (i >= n) return;
    int e = bsums[blockIdx.x] + pref[i];
    indptr[i] = e;
    cursor[i] = e;
}

__global__ void scatter_edges(const int* __restrict__ ei, int* __restrict__ cursor,
                              int* __restrict__ col, int E, int N) {
    int t = blockIdx.x * blockDim.x + threadIdx.x;
    if (t >= E + N) return;
    int src, dst;
    if (t < E) { src = ei[t]; dst = ei[E + t]; }
    else       { src = dst = t - E; }
    int pos = atomicAdd(&cursor[dst], 1);
    col[pos] = src;
}

// ---------------- fused one-shot weight prep --------------------------------
// bt layout per layer: bt[btOff + m*KA + h*Kp + k] = fp16(W[k*HC + h*C + m])
// wesed[weOff + k*2H + o] = sum_c W[k,h*C+c]*a[h,c]  (h=o%H, a=as/ad by o<H).
// wcomb (layer 4, 128x64): cols 0..31 = es/ed weights, cols 32..63 = W4 cols.
__global__ __launch_bounds__(256) void prep_all(
        const float* __restrict__ W0, const float* __restrict__ W1,
        const float* __restrict__ W2, const float* __restrict__ W3,
        const float* __restrict__ W4,
        const float* __restrict__ as0, const float* __restrict__ as1,
        const float* __restrict__ as2, const float* __restrict__ as3,
        const float* __restrict__ as4,
        const float* __restrict__ ad0, const float* __restrict__ ad1,
        const float* __restrict__ ad2, const float* __restrict__ ad3,
        const float* __restrict__ ad4,
        unsigned short* __restrict__ bt, float* __restrict__ wesed,
        float* __restrict__ wcomb) {
    const int Kc[5]  = {34, 64, 128, 256, 128};
    const int Kpc[5] = {64, 64, 128, 256, 128};        // L0 padded to 64
    const int Hc[5]  = {8, 16, 8, 8, 16};
    const int Cc[5]  = {64, 128, 256, 128, 2};
    const int HCc[5] = {512, 2048, 2048, 1024, 32};
    const int KAc[5] = {512, 1024, 1024, 2048, 2048};  // L0 KA = 8*64
    const int btOff[5] = {0, 32768, 163840, 425984, 0};
    const int weOff[5] = {0, 1024, 3072, 5120, 9216};

    int b = blockIdx.x, tid = threadIdx.x;

    if (b < 168) {
        // ---- LDS-tiled transpose, one (layer, head, 64x64 tile) per block --
        int lyr, tloc;
        if (b < 8)        { lyr = 0; tloc = b; }
        else if (b < 40)  { lyr = 1; tloc = b - 8; }
        else if (b < 104) { lyr = 2; tloc = b - 40; }
        else              { lyr = 3; tloc = b - 104; }
        const int ktl[4] = {1, 1, 2, 4};   // ceil(Kp/64)
        const int mtl[4] = {1, 2, 4, 2};   // ceil(C/64)
        int kt = ktl[lyr], mt = mtl[lyr];
        int per_h = kt * mt;
        int h = tloc / per_h, r = tloc - h * per_h;
        int ki = r % kt, mi = r / kt;
        int k0 = ki * 64, m0 = mi * 64;
        int K = Kc[lyr], Kp = Kpc[lyr], C = Cc[lyr], HC = HCc[lyr], KA = KAc[lyr];
        const float* W;
        if (lyr == 0) W = W0; else if (lyr == 1) W = W1;
        else if (lyr == 2) W = W2; else W = W3;

        __shared__ float tile[64][65];
        int c = tid & 63, rg = tid >> 6;
        for (int r2 = rg; r2 < 64; r2 += 4) {       // coalesced 256B reads
            int k = k0 + r2, m = m0 + c;
            float v = (k < K && m < C) ? W[(size_t)k * HC + h * C + m] : 0.f;
            tile[r2][c] = v;
        }
        __syncthreads();
        unsigned short* bp = bt + btOff[lyr];
        for (int mr = rg; mr < 64; mr += 4) {       // coalesced 128B fp16 writes
            int m = m0 + mr, k = k0 + c;
            if (m < C && k < Kp)
                bp[(size_t)m * KA + h * Kp + k] =
                    __half_as_ushort(__float2half(tile[c][mr]));
        }
    } else if (b < 200) {
        // ---- wcomb for layer 4: 8192 outputs (128 x 64) ----
        int u = (b - 168) * 256 + tid;
        int k = u >> 6, o = u & 63;
        float s;
        if (o < 32) {                       // es/ed weights
            int h = (o < 16) ? o : o - 16;
            const float* av = ((o < 16) ? as4 : ad4) + h * 2;
            s = W4[k * 32 + h * 2 + 0] * av[0] + W4[k * 32 + h * 2 + 1] * av[1];
        } else {                            // y projection: raw W4 column
            s = W4[k * 32 + (o - 32)];
        }
        wcomb[u] = s;
    } else {
        // ---- wesed dots: sizes {1024,2048,2048,4096,4096} -> 52 blocks ----
        int wb = b - 200;
        int lyr, u0;
        if (wb < 4)       { lyr = 0; u0 = wb * 256; }
        else if (wb < 12) { lyr = 1; u0 = (wb - 4) * 256; }
        else if (wb < 20) { lyr = 2; u0 = (wb - 12) * 256; }
        else if (wb < 36) { lyr = 3; u0 = (wb - 20) * 256; }
        else              { lyr = 4; u0 = (wb - 36) * 256; }
        int u = u0 + tid;
        int K = Kc[lyr], Kp = Kpc[lyr], H = Hc[lyr], C = Cc[lyr], HC = HCc[lyr];
        int H2 = 2 * H;
        if (u < Kp * H2) {
            int k = u / H2, o = u - k * H2;
            float s = 0.f;
            if (k < K) {
                int h = (o < H) ? o : o - H;
                const float *W, *as_, *ad_;
                if (lyr == 0)      { W = W0; as_ = as0; ad_ = ad0; }
                else if (lyr == 1) { W = W1; as_ = as1; ad_ = ad1; }
                else if (lyr == 2) { W = W2; as_ = as2; ad_ = ad2; }
                else if (lyr == 3) { W = W3; as_ = as3; ad_ = ad3; }
                else               { W = W4; as_ = as4; ad_ = ad4; }
                const float* av = ((o < H) ? as_ : ad_) + h * C;
                const float* wp = W + (size_t)k * HC + h * C;
#pragma unroll 4
                for (int c2 = 0; c2 < C; ++c2) s += wp[c2] * av[c2];
            }
            wesed[weOff[lyr] + u] = s;
        }
    }
}

// ---------------- es/ed (and eyp): out[n,o] = hin16[n,:] @ w[:,o] -----------
__global__ void esed_kernel(const __half* __restrict__ hin, const float* __restrict__ wesed,
                            float* __restrict__ esed, int N, int Kp, int H2) {
    int t = blockIdx.x * blockDim.x + threadIdx.x;
    if (t >= N * H2) return;
    int n = t / H2, o = t - n * H2;
    const __half2* hp = (const __half2*)(hin + (size_t)n * Kp);
    float s = 0.f;
    for (int k2 = 0; k2 < Kp / 2; ++k2) {
        float2 f = __half22float2(hp[k2]);
        s += f.x * wesed[(2 * k2) * H2 + o] + f.y * wesed[(2 * k2 + 1) * H2 + o];
    }
    esed[t] = s;
}

// -------- fused attn+gather via LDS broadcast, pipelined (layers 0-3) -------
// TPN = KP/CH lanes per node. Per chunk of EC = TPN/H edges:
//   p for chunk i+1's attention loads are ISSUED before phase B of chunk i
//   (exp evaluated after phase B, when loads have landed). lds_p is
//   double-buffered so no trailing wave_barrier is needed.
template <int H, int KP, int CH, int NPB>
__global__ __launch_bounds__(NPB * (KP / CH)) void gat_fused_lds(
        const __half* __restrict__ hinf, const float* __restrict__ esed,
        const int* __restrict__ indptr, const int* __restrict__ col,
        __half* __restrict__ g, int N) {
    const int TPN = KP / CH;
    const int EC  = TPN / H;
    const int H2  = 2 * H;
    __shared__ float lds_p[NPB][2][TPN];
    int sub = threadIdx.x / TPN;
    int j   = threadIdx.x % TPN;
    int n = blockIdx.x * NPB + sub;
    if (n >= N) return;
    int e_my = j / H, h_my = j % H;
    int c0 = j * CH;
    float edv = esed[n * H2 + H + h_my];

    float acc[H][CH];
#pragma unroll
    for (int h = 0; h < H; ++h)
#pragma unroll
        for (int t = 0; t < CH; ++t) acc[h][t] = 0.f;
    float zloc = 0.f;

    int beg = indptr[n], deg = indptr[n + 1] - beg;

    // prologue: p for chunk 0
    float p = 0.f;
    if (e_my < deg) {
        int srcm = col[beg + e_my];
        p = expf(lrelu02(esed[srcm * H2 + h_my] + edv));
    }
    int buf = 0;
    for (int base = 0; base < deg; base += EC) {
        zloc += p;
        lds_p[sub][buf][j] = p;
        __builtin_amdgcn_wave_barrier();
        // issue next chunk's attention loads (exp after phase B)
        int ce = base + EC + e_my;
        bool vnext = (ce < deg);
        float esv = 0.f;
        if (vnext) {
            int srcm = col[beg + ce];
            esv = esed[srcm * H2 + h_my];
        }
        // phase B: pipelined gather with LDS-broadcast alphas
#pragma unroll
        for (int e = 0; e < EC; ++e) {
            int idx = base + e;
            if (idx < deg) {                  // uniform within node group
                int src = col[beg + idx];
                float f[CH];
                if (CH == 2) {
                    __half2 hv = *(const __half2*)(hinf + (size_t)src * KP + c0);
                    float2 ff = __half22float2(hv);
                    f[0] = ff.x; f[1] = ff.y;
                } else {
                    half4v hv = *(const half4v*)(hinf + (size_t)src * KP + c0);
                    f[0] = (float)hv[0]; f[1] = (float)hv[1];
                    f[2] = (float)hv[2]; f[3] = (float)hv[3];
                }
                const float4* ap = (const float4*)&lds_p[sub][buf][e * H];
#pragma unroll
                for (int q4 = 0; q4 < H / 4; ++q4) {
                    float4 a4 = ap[q4];
#pragma unroll
                    for (int t = 0; t < CH; ++t) {
                        acc[4 * q4 + 0][t] += a4.x * f[t];
                        acc[4 * q4 + 1][t] += a4.y * f[t];
                        acc[4 * q4 + 2][t] += a4.z * f[t];
                        acc[4 * q4 + 3][t] += a4.w * f[t];
                    }
                }
            }
        }
        p = vnext ? expf(lrelu02(esv + edv)) : 0.f;
        buf ^= 1;
    }

    // z: reduce across the EC lanes of each head class
#pragma unroll
    for (int off = H; off < TPN; off <<= 1)
        zloc += __shfl_xor(zloc, off, TPN);
    float zinv_my = (1.f / H) / (zloc + 1e-16f);

    __half* gp = g + (size_t)n * (H * KP) + c0;
#pragma unroll
    for (int h = 0; h < H; ++h) {
        float zf = __shfl(zinv_my, h, TPN);   // lane class h holds z for head h
        if (CH == 2) {
            *(__half2*)(gp + h * KP) =
                __floats2half2_rn(acc[h][0] * zf, acc[h][1] * zf);
        } else {
            __half2 lo = __floats2half2_rn(acc[h][0] * zf, acc[h][1] * zf);
            __half2 hi = __floats2half2_rn(acc[h][2] * zf, acc[h][3] * zf);
            union { __half2 h2[2]; float2 f2; } u;
            u.h2[0] = lo; u.h2[1] = hi;
            *(float2*)(gp + h * KP) = u.f2;
        }
    }
}

// -------- layer 4: fused attention + projected gather + output --------------
template <int NPB>
__global__ __launch_bounds__(NPB * 32) void final_attn(
        const float* __restrict__ eyp, const int* __restrict__ indptr,
        const int* __restrict__ col, const float* __restrict__ b5,
        const unsigned* __restrict__ masks, const float* __restrict__ x,
        float* __restrict__ outp, int N) {
    int sub = threadIdx.x >> 5;
    int j   = threadIdx.x & 31;
    int n = blockIdx.x * NPB + sub;
    if (n >= N) return;
    int h = j >> 1;
    float edv = eyp[(size_t)n * 64 + 16 + h];
    int beg = indptr[n], end = indptr[n + 1];
    float z = 0.f, a = 0.f;
    int i = beg;
    for (; i + 1 < end; i += 2) {
        int s0 = col[i], s1 = col[i + 1];
        const float* r0 = eyp + (size_t)s0 * 64;
        const float* r1 = eyp + (size_t)s1 * 64;
        float es0 = r0[h], y0 = r0[32 + j];
        float es1 = r1[h], y1 = r1[32 + j];
        float p0 = expf(lrelu02(es0 + edv));
        float p1 = expf(lrelu02(es1 + edv));
        z += p0; a += p0 * y0;
        z += p1; a += p1 * y1;
    }
    for (; i < end; ++i) {
        const float* r = eyp + (size_t)col[i] * 64;
        float p = expf(lrelu02(r[h] + edv));
        z += p; a += p * r[32 + j];
    }
    float zf = (1.f / 16.f) / (z + 1e-16f);
    float val = a * zf;
#pragma unroll
    for (int off = 2; off <= 16; off <<= 1) val += __shfl_xor(val, off, 32);
    float other = __shfl_xor(val, 1, 32);        // opposite parity's sum
    if (j == 0) {
        unsigned mk = masks[n];
        float v0 = x[n * 10 + 0] + selu_f(val + b5[0]);
        float v1 = x[n * 10 + 1] + selu_f(other + b5[1]);
        if (mk & 2u) v0 = 0.f; else if (mk & 1u) v0 = 1.f;
        if (mk & 8u) v1 = 1.f; else if (mk & 4u) v1 = 0.f;
        outp[n * 2 + 0] = v0;
        outp[n * 2 + 1] = v1;
    }
}

// ---------------- LDS-staged f16 MFMA GEMMs ---------------------------------
#define LDP 72

// 64x64 tile (layer 0, C=64). Unchanged from R27.
__global__ __launch_bounds__(256) void gemm_lds(const __half* __restrict__ A,
                                                const unsigned short* __restrict__ Bhi,
                                                const float* __restrict__ bias,
                                                const unsigned* __restrict__ masks,
                                                __half* __restrict__ O16,
                                                int N, int K, int M) {
    __shared__ __half lA[64 * LDP], lB[64 * LDP];
    int tid = threadIdx.x;
    int wave = tid >> 6, lane = tid & 63;
    int ln16 = lane & 15, q = lane >> 4;
    int row0 = blockIdx.x * 64;
    int col0 = blockIdx.y * 64;

    int r0 = tid >> 3, r1 = r0 + 32;
    int ac = (tid & 7) * 8;
    int ga0 = min(row0 + r0, N - 1);
    int ga1 = min(row0 + r1, N - 1);
    const __half* Bp = (const __half*)Bhi;
    const __half* a0p = A + (size_t)ga0 * K + ac;
    const __half* a1p = A + (size_t)ga1 * K + ac;
    const __half* b0p = Bp + (size_t)(col0 + r0) * K + ac;
    const __half* b1p = Bp + (size_t)(col0 + r1) * K + ac;

    half8 ra0 = *(const half8*)(a0p);
    half8 ra1 = *(const half8*)(a1p);
    half8 rb0 = *(const half8*)(b0p);
    half8 rb1 = *(const half8*)(b1p);

    f32x4 acc[4];
#pragma unroll
    for (int j = 0; j < 4; ++j) acc[j] = (f32x4){0.f, 0.f, 0.f, 0.f};

    for (int kc = 0; kc < K; kc += 64) {
        __syncthreads();
        *(half8*)(lA + r0 * LDP + ac) = ra0;
        *(half8*)(lA + r1 * LDP + ac) = ra1;
        *(half8*)(lB + r0 * LDP + ac) = rb0;
        *(half8*)(lB + r1 * LDP + ac) = rb1;
        __syncthreads();
        int kn = kc + 64;
        if (kn < K) {
            ra0 = *(const half8*)(a0p + kn);
            ra1 = *(const half8*)(a1p + kn);
            rb0 = *(const half8*)(b0p + kn);
            rb1 = *(const half8*)(b1p + kn);
        }
#pragma unroll
        for (int kk = 0; kk < 2; ++kk) {
            half8 af = *(const half8*)(lA + (wave * 16 + ln16) * LDP + kk * 32 + q * 8);
#pragma unroll
            for (int j = 0; j < 4; ++j) {
                half8 bf = *(const half8*)(lB + (j * 16 + ln16) * LDP + kk * 32 + q * 8);
                acc[j] = __builtin_amdgcn_mfma_f32_16x16x32_f16(af, bf, acc[j], 0, 0, 0);
            }
        }
    }

#pragma unroll
    for (int j = 0; j < 4; ++j) {
        int cc = col0 + j * 16 + ln16;
        float bv = bias[cc];
#pragma unroll
        for (int r = 0; r < 4; ++r) {
            int rr = row0 + wave * 16 + q * 4 + r;
            if (rr >= N) continue;
            float v = selu_f(acc[j][r] + bv);
            if (cc < 2) {
                unsigned mk = masks[rr];
                if (cc == 0) { if (mk & 2u) v = 0.f; else if (mk & 1u) v = 1.f; }
                else         { if (mk & 8u) v = 1.f; else if (mk & 4u) v = 0.f; }
            }
            O16[(size_t)rr * M + cc] = __float2half(v);
        }
    }
}

// 32x128 tile (layers 1-3): halves A-reads, grid (ceil(N/32), C/128) = 313*y
// blocks. 4 waves: wave w -> rows (w>>1)*16, cols (w&1)*64; per-wave shape
// identical to gemm_lds (bit-identical MFMA accumulation per output).
__global__ __launch_bounds__(256) void gemm_rc(const __half* __restrict__ A,
                                               const unsigned short* __restrict__ Bhi,
                                               const float* __restrict__ bias,
                                               const unsigned* __restrict__ masks,
                                               __half* __restrict__ O16,
                                               int N, int K, int M) {
    __shared__ __half lA[32 * LDP], lB[128 * LDP];
    int tid = threadIdx.x;
    int wave = tid >> 6, lane = tid & 63;
    int ln16 = lane & 15, q = lane >> 4;
    int row0 = blockIdx.x * 32;
    int col0 = blockIdx.y * 128;
    int wr = (wave >> 1) * 16;
    int wc = (wave & 1) * 64;

    int ar = tid >> 3;                       // 0..31
    int ac = (tid & 7) * 8;
    int ga = min(row0 + ar, N - 1);
    const __half* ap  = A + (size_t)ga * K + ac;
    const __half* Bp  = (const __half*)Bhi;
    const __half* b0p = Bp + (size_t)(col0 + ar) * K + ac;
    const __half* b1p = Bp + (size_t)(col0 + ar + 32) * K + ac;
    const __half* b2p = Bp + (size_t)(col0 + ar + 64) * K + ac;
    const __half* b3p = Bp + (size_t)(col0 + ar + 96) * K + ac;

    half8 ra  = *(const half8*)(ap);
    half8 rb0 = *(const half8*)(b0p);
    half8 rb1 = *(const half8*)(b1p);
    half8 rb2 = *(const half8*)(b2p);
    half8 rb3 = *(const half8*)(b3p);

    f32x4 acc[4];
#pragma unroll
    for (int j = 0; j < 4; ++j) acc[j] = (f32x4){0.f, 0.f, 0.f, 0.f};

    for (int kc = 0; kc < K; kc += 64) {
        __syncthreads();
        *(half8*)(lA + ar * LDP + ac)        = ra;
        *(half8*)(lB + ar * LDP + ac)        = rb0;
        *(half8*)(lB + (ar + 32) * LDP + ac) = rb1;
        *(half8*)(lB + (ar + 64) * LDP + ac) = rb2;
        *(half8*)(lB + (ar + 96) * LDP + ac) = rb3;
        __syncthreads();
        int kn = kc + 64;
        if (kn < K) {
            ra  = *(const half8*)(ap + kn);
            rb0 = *(const half8*)(b0p + kn);
            rb1 = *(const half8*)(b1p + kn);
            rb2 = *(const half8*)(b2p + kn);
            rb3 = *(const half8*)(b3p + kn);
        }
#pragma unroll
        for (int kk = 0; kk < 2; ++kk) {
            half8 af = *(const half8*)(lA + (wr + ln16) * LDP + kk * 32 + q * 8);
#pragma unroll
            for (int j = 0; j < 4; ++j) {
                half8 bf = *(const half8*)(lB + (wc + j * 16 + ln16) * LDP + kk * 32 + q * 8);
                acc[j] = __builtin_amdgcn_mfma_f32_16x16x32_f16(af, bf, acc[j], 0, 0, 0);
            }
        }
    }

#pragma unroll
    for (int j = 0; j < 4; ++j) {
        int cc = col0 + wc + j * 16 + ln16;
        float bv = bias[cc];
#pragma unroll
        for (int r = 0; r < 4; ++r) {
            int rr = row0 + wr + q * 4 + r;
            if (rr >= N) continue;
            float v = selu_f(acc[j][r] + bv);
            if (cc < 2) {
                unsigned mk = masks[rr];
                if (cc == 0) { if (mk & 2u) v = 0.f; else if (mk & 1u) v = 1.f; }
                else         { if (mk & 8u) v = 1.f; else if (mk & 4u) v = 0.f; }
            }
            O16[(size_t)rr * M + cc] = __float2half(v);
        }
    }
}

// ---------------------------------------------------------------------------
extern "C" void kernel_launch(void* const* d_in, const int* in_sizes, int n_in,
                              void* d_out, int out_size, void* d_ws, size_t ws_size,
                              hipStream_t stream) {
    const float* x   = (const float*)d_in[0];
    const int*   ei  = (const int*)d_in[1];
    const float* cf  = (const float*)d_in[2];
    const float* cw[4] = {(const float*)d_in[3], (const float*)d_in[5],
                          (const float*)d_in[7], (const float*)d_in[9]};
    const float* cb[4] = {(const float*)d_in[4], (const float*)d_in[6],
                          (const float*)d_in[8], (const float*)d_in[10]};
    const float* gw[5], *gas[5], *gad[5], *gb[5];
    for (int i = 0; i < 5; ++i) {
        gw[i]  = (const float*)d_in[11 + 4 * i];
        gas[i] = (const float*)d_in[12 + 4 * i];
        gad[i] = (const float*)d_in[13 + 4 * i];
        gb[i]  = (const float*)d_in[14 + 4 * i];
    }
    const int N = in_sizes[0] / 10;        // 10000
    const int E = in_sizes[1] / 2;         // 160000
    const int EN = E + N;
    const int NB = (N + 255) / 256;        // scan blocks (40)

    // ---- workspace carve-up ----
    char* base = (char*)d_ws;
    size_t off = 0;
    auto alloc = [&](size_t bytes) -> char* {
        char* p = base + off;
        off = (off + bytes + 255) & ~(size_t)255;
        return p;
    };
    float* cfp   = (float*)alloc((size_t)4 * PSZ * 4);
    float* c1p   = (float*)alloc((size_t)16 * PSZ * 4);
    float* c2p   = (float*)alloc((size_t)32 * PSZ * 4);
    float* c3p   = (float*)alloc((size_t)64 * PSZ * 4);
    float* c4p   = (float*)alloc((size_t)24 * PSZ * 4);
    float* gfeat = (float*)alloc(24 * 4);
    __half* hA16 = (__half*)alloc((size_t)N * 256 * 2);
    __half* hB16 = (__half*)alloc((size_t)N * 256 * 2);
    __half* g    = (__half*)alloc((size_t)N * 2048 * 2);
    float* esed  = (float*)alloc((size_t)N * 32 * 4);
    float* eyp   = (float*)alloc((size_t)N * 64 * 4);        // L4 [es|ed|y]
    float* wesed = (float*)alloc((size_t)13312 * 4);         // layers 0-4
    float* wcomb = (float*)alloc((size_t)8192 * 4);          // L4 combined weights
    unsigned short* bt = (unsigned short*)alloc((size_t)688128 * 2);  // 4 GEMM layers
    unsigned* masks = (unsigned*)alloc((size_t)N * 4);
    int* cnt    = (int*)alloc((size_t)N * 4);
    int* pref   = (int*)alloc((size_t)N * 4);
    int* bsums  = (int*)alloc(64 * 4);
    int* indptr = (int*)alloc((size_t)(N + 1) * 4);
    int* cursor = (int*)alloc((size_t)N * 4);
    int* col    = (int*)alloc((size_t)EN * 4);
    (void)ws_size; // ~70 MB

    // ---- one-shot fused weight prep (all 5 layers) ----
    prep_all<<<252, 256, 0, stream>>>(gw[0], gw[1], gw[2], gw[3], gw[4],
                                      gas[0], gas[1], gas[2], gas[3], gas[4],
                                      gad[0], gad[1], gad[2], gad[3], gad[4],
                                      bt, wesed, wcomb);

    // ---- CNN (padded layout; single memset zeroes all borders) ----
    hipMemsetAsync(cfp, 0, (size_t)140 * PSZ * 4, stream);
    pad_input<<<(4 * 4096 + 255) / 256, 256, 0, stream>>>(cf, cfp);
    conv3x3_pad<4><<<dim3(16, 16), 256, 0, stream>>>(cfp, cw[0], cb[0], c1p);
    conv3x3_pad<16><<<dim3(16, 32), 256, 0, stream>>>(c1p, cw[1], cb[1], c2p);
    conv3x3_pad<32><<<dim3(16, 64), 256, 0, stream>>>(c2p, cw[2], cb[2], c3p);
    conv3x3_pad<64><<<dim3(16, 24), 256, 0, stream>>>(c3p, cw[3], cb[3], c4p);
    avgpool_c<<<24, 256, 0, stream>>>(c4p, gfeat);

    // ---- h0 (padded to 64, fp16) + masks ----
    build_h0<<<(N + 255) / 256, 256, 0, stream>>>(x, gfeat, hA16, masks, N);

    // ---- CSR by dst (incl self loops), parallel scan ----
    hipMemsetAsync(cnt, 0, (size_t)N * 4, stream);
    count_dst<<<(EN + 255) / 256, 256, 0, stream>>>(ei, cnt, E, N);
    scan_blocks<<<NB, 256, 0, stream>>>(cnt, pref, bsums, N);
    scan_sums<<<1, 64, 0, stream>>>(bsums, NB);
    scan_apply<<<NB, 256, 0, stream>>>(pref, bsums, indptr, cursor, N, EN);
    scatter_edges<<<(EN + 255) / 256, 256, 0, stream>>>(ei, cursor, col, E, N);

    // ---- GAT layers ----
    const int Hs[5] = {8, 16, 8, 8, 16};
    const int Cs[5] = {64, 128, 256, 128, 2};
    const int Kp[5] = {64, 64, 128, 256, 128};
    const int btOffA[5] = {0, 32768, 163840, 425984, 0};
    const int weOffA[5] = {0, 1024, 3072, 5120, 9216};

    const __half* hin16 = hA16;
    __half* hout16[4]  = {hB16, hA16, hB16, hA16};

    for (int lyr = 0; lyr < 5; ++lyr) {
        int KP = Kp[lyr], H = Hs[lyr], C = Cs[lyr];
        int KA = H * KP;
        if (lyr == 4) {
            // project-first fused final layer
            esed_kernel<<<(N * 64 + 255) / 256, 256, 0, stream>>>(hin16, wcomb, eyp,
                                                                  N, 128, 64);
            final_attn<8><<<(N + 7) / 8, 256, 0, stream>>>(eyp, indptr, col, gb[4],
                                                           masks, x, (float*)d_out, N);
            break;
        }
        esed_kernel<<<(N * 2 * H + 255) / 256, 256, 0, stream>>>(hin16, wesed + weOffA[lyr],
                                                                 esed, N, KP, 2 * H);
        if (lyr == 0) {
            gat_fused_lds<8, 64, 4, 16><<<(N + 15) / 16, 256, 0, stream>>>(
                hin16, esed, indptr, col, g, N);
        } else if (lyr == 1) {
            gat_fused_lds<16, 64, 2, 8><<<(N + 7) / 8, 256, 0, stream>>>(
                hin16, esed, indptr, col, g, N);
        } else if (lyr == 2) {
            gat_fused_lds<8, 128, 4, 8><<<(N + 7) / 8, 256, 0, stream>>>(
                hin16, esed, indptr, col, g, N);
        } else {
            gat_fused_lds<8, 256, 4, 4><<<(N + 3) / 4, 256, 0, stream>>>(
                hin16, esed, indptr, col, g, N);
        }

        const unsigned short* btL = bt + btOffA[lyr];
        if (lyr == 0) {
            gemm_lds<<<dim3((N + 63) / 64, 1), 256, 0, stream>>>(g, btL, gb[lyr], masks,
                                                                 hout16[lyr], N, KA, C);
        } else {
            gemm_rc<<<dim3((N + 31) / 32, C / 128), 256, 0, stream>>>(g, btL, gb[lyr], masks,
                                                                      hout16[lyr], N, KA, C);
        }
        hin16 = hout16[lyr];
    }
}